// Round 9
// baseline (670.422 us; speedup 1.0000x reference)
//
#include <hip/hip_runtime.h>
#include <hip/hip_bf16.h>
#include <math.h>

// Problem constants
#define NNODES 10000
#define NEDGE  160000
// MULT=16, NL=2, DIM=4, EDGE_DIM=32, HID=128, RANK=8, H=4, HM=4

typedef unsigned short u16;
using bf16x8 = __attribute__((ext_vector_type(8))) short;
using u16x8  = __attribute__((ext_vector_type(8))) unsigned short;
using f32x4  = __attribute__((ext_vector_type(4))) float;

static __device__ __forceinline__ u16 f2bf(float x) {
  unsigned u = __float_as_uint(x);
  u += 0x7FFFu + ((u >> 16) & 1u);     // RNE
  return (u16)(u >> 16);
}
static __device__ __forceinline__ float bf2f(u16 h) {
  return __uint_as_float(((unsigned)h) << 16);
}
// packed RNE f32x2 -> bf16x2 (gfx950 v_cvt_pk_bf16_f32 via HIP API)
static __device__ __forceinline__ unsigned pack_bf16(float a, float b) {
  __hip_bfloat162 h = __float22bfloat162_rn(make_float2(a, b));
  return *(unsigned*)&h;               // low = a, high = b
}
// tanh-form gelu: x*sigmoid(x*(1.5957691 + 0.0713548*x^2)); |err| < 5e-4 abs.
static __device__ __forceinline__ float fast_gelu(float x) {
  float y = x * __builtin_fmaf(0.07135481283f, x * x, 1.5957691216f);
  float e = __expf(y);
  return x - x * __builtin_amdgcn_rcpf(e + 1.0f);
}
// sum over 16-lane groups, pure DPP (no DS pipe)
static __device__ __forceinline__ float dpp_red16(float p) {
  p += __int_as_float(__builtin_amdgcn_update_dpp(0, __float_as_int(p), 0xB1,  0xF, 0xF, true));
  p += __int_as_float(__builtin_amdgcn_update_dpp(0, __float_as_int(p), 0x4E,  0xF, 0xF, true));
  p += __int_as_float(__builtin_amdgcn_update_dpp(0, __float_as_int(p), 0x141, 0xF, 0xF, true));
  p += __int_as_float(__builtin_amdgcn_update_dpp(0, __float_as_int(p), 0x140, 0xF, 0xF, true));
  return p;
}

// ---------------- zero cnt (must finish before setup's csr_count) -----------
__global__ void zero_cnt_kernel(int* __restrict__ cnt) {
  int i = blockIdx.x * 256 + threadIdx.x;
  if (i < NNODES) cnt[i] = 0;
}

// ---------------- fused setup: prep_w | prep_w1 | q | csr_count -------------
__global__ void __launch_bounds__(256) setup_kernel(
    const float* __restrict__ kwr, const float* __restrict__ kwl,
    const float* __restrict__ vwr, const float* __restrict__ vwl,
    u16* __restrict__ Wsw,
    const float* __restrict__ kw1, const float* __restrict__ vw1,
    u16* __restrict__ W1sw,
    const float* __restrict__ f, const float* __restrict__ qw,
    const float* __restrict__ qb, float* __restrict__ q,
    const int* __restrict__ dst, int* __restrict__ cnt) {
  int b = blockIdx.x, tid = threadIdx.x;
  if (b < 512) {                      // prep_w
    int idx = b * 256 + tid;          // 0..131071  (4 slots x 32768)
    int slot = idx >> 15;
    int w = idx & 32767;
    int j = w & 7, lane = (w >> 3) & 63, ks = (w >> 9) & 3, tg = w >> 11;
    int k   = ks * 32 + ((lane >> 4) << 3) + j;
    int col = (tg << 4) + (lane & 15);
    const float* s = (slot == 0) ? kwr : (slot == 1) ? kwl : (slot == 2) ? vwr : vwl;
    Wsw[idx] = f2bf(s[k * 256 + col]);
  } else if (b < 544) {               // prep_w1
    int idx = (b - 512) * 256 + tid;  // 0..8191 (2 slots x 4096)
    int slot = idx >> 12;
    int w = idx & 4095;
    int j = w & 7, lane = (w >> 3) & 63, nt = w >> 9;
    int k   = ((lane >> 4) << 3) + j;
    int col = (nt << 4) + (lane & 15);
    const float* s = (slot == 0) ? kw1 : vw1;
    W1sw[idx] = f2bf(s[k * 128 + col]);
  } else if (b < 1169) {              // q: 625 blocks
    int i = (b - 544) * 256 + tid;    // n*16 + o
    if (i >= NNODES * 16) return;
    int n = i >> 4, o = i & 15;
    const float* frow = f + (size_t)n * 64;
    float o0 = 0.f, o1 = 0.f, o2 = 0.f, o3 = 0.f;
#pragma unroll
    for (int m = 0; m < 16; ++m) {
      float w0 = qw[o * 16 + m];
      float w1 = qw[(16 + o) * 16 + m];
      o0 += w0 * frow[m * 4 + 0];
      o1 += w1 * frow[m * 4 + 1];
      o2 += w1 * frow[m * 4 + 2];
      o3 += w1 * frow[m * 4 + 3];
    }
    o0 += qb[o];
    float4 r = make_float4(o0, o1, o2, o3);
    *(float4*)(q + (size_t)i * 4) = r;
  } else {                            // csr_count: 625 blocks
    int e = (b - 1169) * 256 + tid;   // exact
    atomicAdd(&cnt[dst[e]], 1);
  }
}

// ---------------- CSR scan ---------------------------------------------------
__global__ void __launch_bounds__(1024) csr_scan_kernel(
    const int* __restrict__ cnt, int* __restrict__ rowptr, int* __restrict__ cursor) {
  __shared__ int part[1024];
  int t = threadIdx.x;
  int base = t * 10;                              // 1024*10 = 10240 >= NNODES
  int s = 0;
#pragma unroll
  for (int i = 0; i < 10; ++i) { int idx = base + i; if (idx < NNODES) s += cnt[idx]; }
  part[t] = s;
  __syncthreads();
  for (int o = 1; o < 1024; o <<= 1) {
    int v = (t >= o) ? part[t - o] : 0;
    __syncthreads();
    part[t] += v;
    __syncthreads();
  }
  int run = (t == 0) ? 0 : part[t - 1];
#pragma unroll
  for (int i = 0; i < 10; ++i) {
    int idx = base + i;
    if (idx < NNODES) { rowptr[idx] = run; cursor[idx] = run; run += cnt[idx]; }
  }
  if (t == 1023) rowptr[NNODES] = run;
}

// ---------------- fill: t | ef(bf16) | b2 into ONE 192B/edge record ---------
// Record layout (pos-ordered): [t: 32 u16][ef: 32 u16][b2: 8 f32] = 160B,
// pitch 192B = 3 full 64B lines -> no partial-sector RMW on scattered writes.
__global__ void __launch_bounds__(256) fill_t_kernel(
    const int* __restrict__ dst, const int* __restrict__ src,
    const float* __restrict__ f, const float* __restrict__ b1,
    const float* __restrict__ b2, const float* __restrict__ ef,
    int* __restrict__ cursor, char* __restrict__ comb) {
  int e = blockIdx.x * 256 + threadIdx.x;        // grid exact
  int pos = atomicAdd(&cursor[dst[e]], 1);
  char* rb = comb + (size_t)pos * 192;
  // t row: t[m,l] = sum_d f[src][m][d] * b1[e][d][l]
  const float* frow = f + (size_t)src[e] * 64;
  const float* be = b1 + (size_t)e * 8;          // (4,2)
  float b[8];
#pragma unroll
  for (int k = 0; k < 8; ++k) b[k] = be[k];
  uint4* tp = (uint4*)rb;
#pragma unroll
  for (int mh = 0; mh < 4; ++mh) {
    unsigned pk[4];
#pragma unroll
    for (int mi = 0; mi < 4; ++mi) {
      int m = mh * 4 + mi;
      float f0 = frow[m * 4 + 0], f1 = frow[m * 4 + 1], f2 = frow[m * 4 + 2], f3 = frow[m * 4 + 3];
      float t0 = f0 * b[0] + f1 * b[2] + f2 * b[4] + f3 * b[6];
      float t1 = f0 * b[1] + f1 * b[3] + f2 * b[5] + f3 * b[7];
      pk[mi] = pack_bf16(t0, t1);
    }
    tp[mh] = make_uint4(pk[0], pk[1], pk[2], pk[3]);
  }
  // ef bf16 cast at +64B
  const float* efe = ef + (size_t)e * 32;
#pragma unroll
  for (int g = 0; g < 4; ++g) {
    float4 v0 = *(const float4*)&efe[g * 8];
    float4 v1 = *(const float4*)&efe[g * 8 + 4];
    tp[4 + g] = make_uint4(pack_bf16(v0.x, v0.y), pack_bf16(v0.z, v0.w),
                           pack_bf16(v1.x, v1.y), pack_bf16(v1.z, v1.w));
  }
  // b2 copy at +128B
  const float* b2e = b2 + (size_t)e * 8;
  *(float4*)(rb + 128) = *(const float4*)&b2e[0];
  *(float4*)(rb + 144) = *(const float4*)&b2e[4];
}

// ---------------- fused equivariant conv (transposed GEMMs) -----------------
// __launch_bounds__(512, 8): force VGPR<=64 so LDS (37 KB) sets the
// occupancy limit (4 blocks/CU). Round 7's 72-VGPR build dropped to
// 3 blocks/CU and regressed 46->60 us.
__global__ void __launch_bounds__(512, 8) conv_fused_kernel(
    const char* __restrict__ comb, const u16* __restrict__ w1sw,
    const float* __restrict__ b1h,
    const u16* __restrict__ wsw_r, const float* __restrict__ br,
    const u16* __restrict__ wsw_l, const float* __restrict__ bl,
    u16* __restrict__ kv) {
  __shared__ alignas(16) u16 sA[64 * 136];    // H tile [edge][hid]
  __shared__ alignas(16) u16 t_s[64 * 40];    // t tile (bf16)
  __shared__ alignas(16) float b2_s[64 * 12];
  __shared__ alignas(16) float u_s[64 * 12];  // u[e][p]
  __shared__ alignas(16) float t2_s[64 * 33]; // t2[e][r2], pitch 33

  int tid = threadIdx.x;
  int wave = tid >> 6, lane = tid & 63, quad = lane >> 4, l16 = lane & 15;
  size_t i0 = (size_t)blockIdx.x * 64;

  // ---- stage t & b2 tiles from comb ----
  if (tid < 256) {            // t tile: 64 rows x 64B
    int row = tid >> 2, seg = tid & 3;
    *(uint4*)&t_s[row * 40 + seg * 8] =
        *(const uint4*)(comb + (i0 + row) * 192 + seg * 16);
  } else if (tid < 384) {     // b2 tile: 64 rows x 32B at +128
    int j = tid - 256, row = j >> 1, half = j & 1;
    *(float4*)&b2_s[row * 12 + half * 4] =
        *(const float4*)(comb + (i0 + row) * 192 + 128 + half * 16);
  }

  // ---- h-stage: wave owns hid-tile `wave`; ef frags direct from comb ----
  {
    bf16x8 aw = *(const bf16x8*)&w1sw[(size_t)(wave * 64 + lane) * 8];  // A = w1^T
    float4 bias_h = *(const float4*)&b1h[wave * 16 + quad * 4];
    f32x4 seed;
    seed[0] = bias_h.x; seed[1] = bias_h.y; seed[2] = bias_h.z; seed[3] = bias_h.w;
#pragma unroll
    for (int nt = 0; nt < 4; ++nt) {
      bf16x8 be = *(const bf16x8*)(comb + (i0 + nt * 16 + l16) * 192 + 64 + quad * 16);
      f32x4 acch = __builtin_amdgcn_mfma_f32_16x16x32_bf16(aw, be, seed, 0, 0, 0);
      unsigned p0 = pack_bf16(fast_gelu(acch[0]), fast_gelu(acch[1]));
      unsigned p1 = pack_bf16(fast_gelu(acch[2]), fast_gelu(acch[3]));
      *(uint2*)&sA[(nt * 16 + l16) * 136 + wave * 16 + quad * 4] = make_uint2(p0, p1);
    }
  }
  __syncthreads();

  // ---- acc seeding with biases: weight-col = (2w+mtl)*16 + 4q + r ----
  f32x4 accr[2][4], accl[2][4];
#pragma unroll
  for (int mtl = 0; mtl < 2; ++mtl) {
    int colb = (wave * 2 + mtl) * 16 + quad * 4;
    float4 brv = *(const float4*)&br[colb];
    float4 blv = *(const float4*)&bl[colb];
#pragma unroll
    for (int nt = 0; nt < 4; ++nt) {
      accr[mtl][nt][0] = brv.x; accr[mtl][nt][1] = brv.y;
      accr[mtl][nt][2] = brv.z; accr[mtl][nt][3] = brv.w;
      accl[mtl][nt][0] = blv.x; accl[mtl][nt][1] = blv.y;
      accl[mtl][nt][2] = blv.z; accl[mtl][nt][3] = blv.w;
    }
  }

  // ---- K-loop: transposed GEMMs (A = weights, B = H) ----
#pragma unroll
  for (int ks = 0; ks < 4; ++ks) {
    bf16x8 bfrag[4];
#pragma unroll
    for (int nt = 0; nt < 4; ++nt)
      bfrag[nt] = *(const bf16x8*)&sA[(nt * 16 + l16) * 136 + ks * 32 + quad * 8];
#pragma unroll
    for (int mtl = 0; mtl < 2; ++mtl) {
      int mtg = wave * 2 + mtl;
      bf16x8 ar = *(const bf16x8*)&wsw_r[(size_t)((mtg * 4 + ks) * 64 + lane) * 8];
      bf16x8 al = *(const bf16x8*)&wsw_l[(size_t)((mtg * 4 + ks) * 64 + lane) * 8];
#pragma unroll
      for (int nt = 0; nt < 4; ++nt) {
        accr[mtl][nt] = __builtin_amdgcn_mfma_f32_16x16x32_bf16(ar, bfrag[nt], accr[mtl][nt], 0, 0, 0);
        accl[mtl][nt] = __builtin_amdgcn_mfma_f32_16x16x32_bf16(al, bfrag[nt], accl[mtl][nt], 0, 0, 0);
      }
    }
  }

  // ---- right epilogue: u[e, p=wave] = sum_c right*t (bias pre-seeded) ----
#pragma unroll
  for (int nt = 0; nt < 4; ++nt) {
    int e = nt * 16 + l16;
    ushort4 ta = *(const ushort4*)&t_s[e * 40 + 4 * quad];        // c: mtl=0
    ushort4 tb = *(const ushort4*)&t_s[e * 40 + 16 + 4 * quad];   // c: mtl=1
    float s = accr[0][nt][0] * bf2f(ta.x)
            + accr[0][nt][1] * bf2f(ta.y)
            + accr[0][nt][2] * bf2f(ta.z)
            + accr[0][nt][3] * bf2f(ta.w)
            + accr[1][nt][0] * bf2f(tb.x)
            + accr[1][nt][1] * bf2f(tb.y)
            + accr[1][nt][2] * bf2f(tb.z)
            + accr[1][nt][3] * bf2f(tb.w);
    s += __shfl_xor(s, 16);
    s += __shfl_xor(s, 32);
    if (quad == 0) u_s[e * 12 + wave] = s;
  }
  __syncthreads();

  // ---- left epilogue: t2[e, r2] = sum_p left*u (bias pre-seeded) ----
#pragma unroll
  for (int nt = 0; nt < 4; ++nt) {
    int e = nt * 16 + l16;
    float4 uv = *(const float4*)&u_s[e * 12 + 4 * (quad & 1)];
#pragma unroll
    for (int mtl = 0; mtl < 2; ++mtl) {
      float s = accl[mtl][nt][0] * uv.x
              + accl[mtl][nt][1] * uv.y
              + accl[mtl][nt][2] * uv.z
              + accl[mtl][nt][3] * uv.w;
      s += __shfl_xor(s, 16);                    // combine p halves (q^1)
      if ((quad & 1) == 0)
        t2_s[e * 33 + 4 * wave + 2 * mtl + (quad >> 1)] = s;
    }
  }
  __syncthreads();

  // ---- kv stage: thread -> (e = tid>>3, j = tid&7) => elements j*8..j*8+7 ----
  {
    int e = tid >> 3, j = tid & 7;
    const float* tp = &t2_s[e * 33 + 4 * j];     // r2 = 4j..4j+3
    float t20 = tp[0], t21 = tp[1], t22 = tp[2], t23 = tp[3];
    float4 b2a = *(const float4*)&b2_s[e * 12 + 0];
    float4 b2b = *(const float4*)&b2_s[e * 12 + 4];
    unsigned q0 = pack_bf16(t20 * b2a.x + t21 * b2b.x, t20 * b2a.y + t21 * b2b.y);
    unsigned q1 = pack_bf16(t20 * b2a.z + t21 * b2b.z, t20 * b2a.w + t21 * b2b.w);
    unsigned q2 = pack_bf16(t22 * b2a.x + t23 * b2b.x, t22 * b2a.y + t23 * b2b.y);
    unsigned q3 = pack_bf16(t22 * b2a.z + t23 * b2b.z, t22 * b2a.w + t23 * b2b.w);
    *(uint4*)&kv[(i0 + e) * 64 + j * 8] = make_uint4(q0, q1, q2, q3);
  }
}

// ---------------- fused attention gather (streaming, DPP, unroll x2) --------
__global__ void __launch_bounds__(256) attn_gather_kernel(
    const float* __restrict__ q, const u16* __restrict__ kvk,
    const u16* __restrict__ kvv, const int* __restrict__ rowptr,
    float* __restrict__ outp) {
  int tid = threadIdx.x;
  int node = blockIdx.x * 4 + (tid >> 6);        // grid 2500 * 4 = NNODES
  int lane = tid & 63;
  float qv = q[(size_t)node * 64 + lane];
  int beg = rowptr[node], end = rowptr[node + 1];
  float num = 0.f, den = 0.f;
  int idx = beg;
  for (; idx + 2 <= end; idx += 2) {             // 2 independent chains
    float kf0 = bf2f(kvk[(size_t)idx * 64 + lane]);
    float kf1 = bf2f(kvk[(size_t)(idx + 1) * 64 + lane]);
    float v0  = bf2f(kvv[(size_t)idx * 64 + lane]);
    float v1  = bf2f(kvv[(size_t)(idx + 1) * 64 + lane]);
    float p0 = dpp_red16(qv * kf0);
    float p1 = dpp_red16(qv * kf1);
    float e0 = __expf(p0 * 0.25f);
    float e1 = __expf(p1 * 0.25f);
    den += e0 + e1;
    num += e0 * v0 + e1 * v1;
  }
  if (idx < end) {
    float kf = bf2f(kvk[(size_t)idx * 64 + lane]);
    float p = dpp_red16(qv * kf);
    float exv = __expf(p * 0.25f);
    den += exv;
    num += exv * bf2f(kvv[(size_t)idx * 64 + lane]);
  }
  outp[(size_t)node * 64 + lane] = num / fmaxf(den, 1e-9f);
}

extern "C" void kernel_launch(void* const* d_in, const int* in_sizes, int n_in,
                              void* d_out, int out_size, void* d_ws, size_t ws_size,
                              hipStream_t stream) {
  const float* b1  = (const float*)d_in[0];
  const float* b2  = (const float*)d_in[1];
  const float* ef  = (const float*)d_in[2];
  const float* f   = (const float*)d_in[3];
  const int*   src = (const int*)d_in[4];
  const int*   dst = (const int*)d_in[5];
  const float* qw  = (const float*)d_in[6];
  const float* qb  = (const float*)d_in[7];
  const float* kw1 = (const float*)d_in[8];
  const float* kb1 = (const float*)d_in[9];
  const float* kwl = (const float*)d_in[10];
  const float* kbl = (const float*)d_in[11];
  const float* kwr = (const float*)d_in[12];
  const float* kbr = (const float*)d_in[13];
  const float* vw1 = (const float*)d_in[14];
  const float* vb1 = (const float*)d_in[15];
  const float* vwl = (const float*)d_in[16];
  const float* vbl = (const float*)d_in[17];
  const float* vwr = (const float*)d_in[18];
  const float* vbr = (const float*)d_in[19];
  float* outp = (float*)d_out;

  // workspace layout
  char* ws = (char*)d_ws;
  size_t off = 0;
  auto alloc = [&](size_t bytes) {
    char* p = ws + off;
    off += (bytes + 511) & ~(size_t)511;
    return p;
  };
  u16*   Wsw  = (u16*)  alloc((size_t)4 * 32768 * 2);
  u16*   W1sw = (u16*)  alloc((size_t)2 * 4096 * 2);
  char*  comb = (char*) alloc((size_t)NEDGE * 192);
  u16*   kvk  = (u16*)  alloc((size_t)NEDGE * 64 * 2);
  u16*   kvv  = (u16*)  alloc((size_t)NEDGE * 64 * 2);
  float* qbuf = (float*)alloc((size_t)NNODES * 64 * 4);
  int*   cnt    = (int*)alloc((size_t)NNODES * 4);
  int*   rowptr = (int*)alloc((size_t)(NNODES + 1) * 4);
  int*   cursor = (int*)alloc((size_t)NNODES * 4);

  // zero counts (kernel, not memset: graph-capture-safe), then fused setup
  zero_cnt_kernel<<<40, 256, 0, stream>>>(cnt);
  setup_kernel<<<1794, 256, 0, stream>>>(kwr, kwl, vwr, vwl, Wsw,
                                         kw1, vw1, W1sw,
                                         f, qw, qb, qbuf, dst, cnt);
  csr_scan_kernel<<<1, 1024, 0, stream>>>(cnt, rowptr, cursor);
  fill_t_kernel<<<625, 256, 0, stream>>>(dst, src, f, b1, b2, ef,
                                         cursor, comb);

  // conv K
  conv_fused_kernel<<<2500, 512, 0, stream>>>(comb, W1sw + 0 * 4096, kb1,
                                              Wsw + 0 * 32768, kbr,
                                              Wsw + 1 * 32768, kbl,
                                              kvk);
  // conv V
  conv_fused_kernel<<<2500, 512, 0, stream>>>(comb, W1sw + 1 * 4096, vb1,
                                              Wsw + 2 * 32768, vbr,
                                              Wsw + 3 * 32768, vbl,
                                              kvv);

  // fused attention (streaming reads, DPP reductions, no atomics)
  attn_gather_kernel<<<2500, 256, 0, stream>>>(qbuf, kvk, kvv, rowptr, outp);
}

// Round 10
// 249.684 us; speedup vs baseline: 2.6851x; 2.6851x over previous
//
#include <hip/hip_runtime.h>
#include <hip/hip_bf16.h>
#include <math.h>

// Problem constants
#define NNODES 10000
#define NEDGE  160000
// MULT=16, NL=2, DIM=4, EDGE_DIM=32, HID=128, RANK=8, H=4, HM=4

typedef unsigned short u16;
using bf16x8 = __attribute__((ext_vector_type(8))) short;
using u16x8  = __attribute__((ext_vector_type(8))) unsigned short;
using f32x4  = __attribute__((ext_vector_type(4))) float;

static __device__ __forceinline__ u16 f2bf(float x) {
  unsigned u = __float_as_uint(x);
  u += 0x7FFFu + ((u >> 16) & 1u);     // RNE
  return (u16)(u >> 16);
}
static __device__ __forceinline__ float bf2f(u16 h) {
  return __uint_as_float(((unsigned)h) << 16);
}
// packed RNE f32x2 -> bf16x2 (gfx950 v_cvt_pk_bf16_f32 via HIP API)
static __device__ __forceinline__ unsigned pack_bf16(float a, float b) {
  __hip_bfloat162 h = __float22bfloat162_rn(make_float2(a, b));
  return *(unsigned*)&h;               // low = a, high = b
}
// tanh-form gelu: x*sigmoid(x*(1.5957691 + 0.0713548*x^2)); |err| < 5e-4 abs.
static __device__ __forceinline__ float fast_gelu(float x) {
  float y = x * __builtin_fmaf(0.07135481283f, x * x, 1.5957691216f);
  float e = __expf(y);
  return x - x * __builtin_amdgcn_rcpf(e + 1.0f);
}
// sum over 16-lane groups, pure DPP (no DS pipe)
static __device__ __forceinline__ float dpp_red16(float p) {
  p += __int_as_float(__builtin_amdgcn_update_dpp(0, __float_as_int(p), 0xB1,  0xF, 0xF, true));
  p += __int_as_float(__builtin_amdgcn_update_dpp(0, __float_as_int(p), 0x4E,  0xF, 0xF, true));
  p += __int_as_float(__builtin_amdgcn_update_dpp(0, __float_as_int(p), 0x141, 0xF, 0xF, true));
  p += __int_as_float(__builtin_amdgcn_update_dpp(0, __float_as_int(p), 0x140, 0xF, 0xF, true));
  return p;
}

// ---------------- zero cnt (must finish before setup's csr_count) -----------
__global__ void zero_cnt_kernel(int* __restrict__ cnt) {
  int i = blockIdx.x * 256 + threadIdx.x;
  if (i < NNODES) cnt[i] = 0;
}

// ---------------- fused setup: prep_w | prep_w1 | q | csr_count -------------
__global__ void __launch_bounds__(256) setup_kernel(
    const float* __restrict__ kwr, const float* __restrict__ kwl,
    const float* __restrict__ vwr, const float* __restrict__ vwl,
    u16* __restrict__ Wsw,
    const float* __restrict__ kw1, const float* __restrict__ vw1,
    u16* __restrict__ W1sw,
    const float* __restrict__ f, const float* __restrict__ qw,
    const float* __restrict__ qb, float* __restrict__ q,
    const int* __restrict__ dst, int* __restrict__ cnt) {
  int b = blockIdx.x, tid = threadIdx.x;
  if (b < 512) {                      // prep_w
    int idx = b * 256 + tid;          // 0..131071  (4 slots x 32768)
    int slot = idx >> 15;
    int w = idx & 32767;
    int j = w & 7, lane = (w >> 3) & 63, ks = (w >> 9) & 3, tg = w >> 11;
    int k   = ks * 32 + ((lane >> 4) << 3) + j;
    int col = (tg << 4) + (lane & 15);
    const float* s = (slot == 0) ? kwr : (slot == 1) ? kwl : (slot == 2) ? vwr : vwl;
    Wsw[idx] = f2bf(s[k * 256 + col]);
  } else if (b < 544) {               // prep_w1
    int idx = (b - 512) * 256 + tid;  // 0..8191 (2 slots x 4096)
    int slot = idx >> 12;
    int w = idx & 4095;
    int j = w & 7, lane = (w >> 3) & 63, nt = w >> 9;
    int k   = ((lane >> 4) << 3) + j;
    int col = (nt << 4) + (lane & 15);
    const float* s = (slot == 0) ? kw1 : vw1;
    W1sw[idx] = f2bf(s[k * 128 + col]);
  } else if (b < 1169) {              // q: 625 blocks
    int i = (b - 544) * 256 + tid;    // n*16 + o
    if (i >= NNODES * 16) return;
    int n = i >> 4, o = i & 15;
    const float* frow = f + (size_t)n * 64;
    float o0 = 0.f, o1 = 0.f, o2 = 0.f, o3 = 0.f;
#pragma unroll
    for (int m = 0; m < 16; ++m) {
      float w0 = qw[o * 16 + m];
      float w1 = qw[(16 + o) * 16 + m];
      o0 += w0 * frow[m * 4 + 0];
      o1 += w1 * frow[m * 4 + 1];
      o2 += w1 * frow[m * 4 + 2];
      o3 += w1 * frow[m * 4 + 3];
    }
    o0 += qb[o];
    float4 r = make_float4(o0, o1, o2, o3);
    *(float4*)(q + (size_t)i * 4) = r;
  } else {                            // csr_count: 625 blocks
    int e = (b - 1169) * 256 + tid;   // exact
    atomicAdd(&cnt[dst[e]], 1);
  }
}

// ---------------- CSR scan ---------------------------------------------------
__global__ void __launch_bounds__(1024) csr_scan_kernel(
    const int* __restrict__ cnt, int* __restrict__ rowptr, int* __restrict__ cursor) {
  __shared__ int part[1024];
  int t = threadIdx.x;
  int base = t * 10;                              // 1024*10 = 10240 >= NNODES
  int s = 0;
#pragma unroll
  for (int i = 0; i < 10; ++i) { int idx = base + i; if (idx < NNODES) s += cnt[idx]; }
  part[t] = s;
  __syncthreads();
  for (int o = 1; o < 1024; o <<= 1) {
    int v = (t >= o) ? part[t - o] : 0;
    __syncthreads();
    part[t] += v;
    __syncthreads();
  }
  int run = (t == 0) ? 0 : part[t - 1];
#pragma unroll
  for (int i = 0; i < 10; ++i) {
    int idx = base + i;
    if (idx < NNODES) { rowptr[idx] = run; cursor[idx] = run; run += cnt[idx]; }
  }
  if (t == 1023) rowptr[NNODES] = run;
}

// ---------------- fill: t | ef(bf16) | b2 into ONE 192B/edge record ---------
// Record layout (pos-ordered): [t: 32 u16][ef: 32 u16][b2: 8 f32] = 160B,
// pitch 192B = 3 full 64B lines -> no partial-sector RMW on scattered writes.
__global__ void __launch_bounds__(256) fill_t_kernel(
    const int* __restrict__ dst, const int* __restrict__ src,
    const float* __restrict__ f, const float* __restrict__ b1,
    const float* __restrict__ b2, const float* __restrict__ ef,
    int* __restrict__ cursor, char* __restrict__ comb) {
  int e = blockIdx.x * 256 + threadIdx.x;        // grid exact
  int pos = atomicAdd(&cursor[dst[e]], 1);
  char* rb = comb + (size_t)pos * 192;
  // t row: t[m,l] = sum_d f[src][m][d] * b1[e][d][l]
  const float* frow = f + (size_t)src[e] * 64;
  const float* be = b1 + (size_t)e * 8;          // (4,2)
  float b[8];
#pragma unroll
  for (int k = 0; k < 8; ++k) b[k] = be[k];
  uint4* tp = (uint4*)rb;
#pragma unroll
  for (int mh = 0; mh < 4; ++mh) {
    unsigned pk[4];
#pragma unroll
    for (int mi = 0; mi < 4; ++mi) {
      int m = mh * 4 + mi;
      float f0 = frow[m * 4 + 0], f1 = frow[m * 4 + 1], f2 = frow[m * 4 + 2], f3 = frow[m * 4 + 3];
      float t0 = f0 * b[0] + f1 * b[2] + f2 * b[4] + f3 * b[6];
      float t1 = f0 * b[1] + f1 * b[3] + f2 * b[5] + f3 * b[7];
      pk[mi] = pack_bf16(t0, t1);
    }
    tp[mh] = make_uint4(pk[0], pk[1], pk[2], pk[3]);
  }
  // ef bf16 cast at +64B
  const float* efe = ef + (size_t)e * 32;
#pragma unroll
  for (int g = 0; g < 4; ++g) {
    float4 v0 = *(const float4*)&efe[g * 8];
    float4 v1 = *(const float4*)&efe[g * 8 + 4];
    tp[4 + g] = make_uint4(pack_bf16(v0.x, v0.y), pack_bf16(v0.z, v0.w),
                           pack_bf16(v1.x, v1.y), pack_bf16(v1.z, v1.w));
  }
  // b2 copy at +128B
  const float* b2e = b2 + (size_t)e * 8;
  *(float4*)(rb + 128) = *(const float4*)&b2e[0];
  *(float4*)(rb + 144) = *(const float4*)&b2e[4];
}

// ---------------- fused equivariant conv (transposed GEMMs) -----------------
// ROUND-5 BODY (measured 46 us @ VGPR 64) + comb staging.
// NO min-wave launch bound: acc floor is 64 VGPRs (16x f32x4); forcing
// 8 waves/EU (round 8/9) spilled 814 MB scratch and ran 254+ us.
__global__ void __launch_bounds__(512) conv_fused_kernel(
    const char* __restrict__ comb, const u16* __restrict__ w1sw,
    const float* __restrict__ b1h,
    const u16* __restrict__ wsw_r, const float* __restrict__ br,
    const u16* __restrict__ wsw_l, const float* __restrict__ bl,
    u16* __restrict__ kv) {
  __shared__ alignas(16) u16 sA[64 * 136];    // H tile [edge][hid]
  __shared__ alignas(16) u16 t_s[64 * 40];    // t tile (bf16)
  __shared__ alignas(16) float b2_s[64 * 12];
  __shared__ alignas(16) float u_s[64 * 12];  // u[e][p]
  __shared__ alignas(16) float t2_pool[64 * 36]; // t2[e][r2]; overlays efs
  float* t2_s = t2_pool;
  u16*   efs  = (u16*)t2_pool;                // ef tile bf16 [edge][k] pitch 40

  int tid = threadIdx.x;
  int wave = tid >> 6, lane = tid & 63, quad = lane >> 4, l16 = lane & 15;
  size_t i0 = (size_t)blockIdx.x * 64;

  // ---- stage tiles from comb ----
  if (tid < 256) {            // ef tile: 64 rows x 64B at +64
    int row = tid >> 2, seg = tid & 3;
    *(uint4*)&efs[row * 40 + seg * 8] =
        *(const uint4*)(comb + (i0 + row) * 192 + 64 + seg * 16);
    if (tid < 128) {          // b2 tile: 64 rows x 32B at +128
      int r2 = tid >> 1, half = tid & 1;
      *(float4*)&b2_s[r2 * 12 + half * 4] =
          *(const float4*)(comb + (i0 + r2) * 192 + 128 + half * 16);
    }
  } else {                    // t tile: 64 rows x 64B at +0
    int j = tid - 256;
    int row = j >> 2, seg = j & 3;
    *(uint4*)&t_s[row * 40 + seg * 8] =
        *(const uint4*)(comb + (i0 + row) * 192 + seg * 16);
  }
  __syncthreads();

  // ---- h-stage: wave owns hid-tile `wave` (16 cols), 4 edge tiles ----
  {
    bf16x8 aw = *(const bf16x8*)&w1sw[(size_t)(wave * 64 + lane) * 8];  // A = w1^T
    float4 bias_h = *(const float4*)&b1h[wave * 16 + quad * 4];
#pragma unroll
    for (int nt = 0; nt < 4; ++nt) {
      bf16x8 be = *(const bf16x8*)&efs[(nt * 16 + l16) * 40 + quad * 8]; // B = ef^T
      f32x4 acch = __builtin_amdgcn_mfma_f32_16x16x32_bf16(aw, be, (f32x4){0.f, 0.f, 0.f, 0.f}, 0, 0, 0);
      unsigned p0 = pack_bf16(fast_gelu(acch[0] + bias_h.x), fast_gelu(acch[1] + bias_h.y));
      unsigned p1 = pack_bf16(fast_gelu(acch[2] + bias_h.z), fast_gelu(acch[3] + bias_h.w));
      *(uint2*)&sA[(nt * 16 + l16) * 136 + wave * 16 + quad * 4] = make_uint2(p0, p1);
    }
  }
  __syncthreads();

  // ---- K-loop: transposed GEMMs (A = weights, B = H), zero-seeded accs ----
  f32x4 accr[2][4], accl[2][4];
#pragma unroll
  for (int mtl = 0; mtl < 2; ++mtl)
#pragma unroll
    for (int nt = 0; nt < 4; ++nt) {
      accr[mtl][nt] = (f32x4){0.f, 0.f, 0.f, 0.f};
      accl[mtl][nt] = (f32x4){0.f, 0.f, 0.f, 0.f};
    }
#pragma unroll
  for (int ks = 0; ks < 4; ++ks) {
    bf16x8 bfrag[4];
#pragma unroll
    for (int nt = 0; nt < 4; ++nt)
      bfrag[nt] = *(const bf16x8*)&sA[(nt * 16 + l16) * 136 + ks * 32 + quad * 8];
#pragma unroll
    for (int mtl = 0; mtl < 2; ++mtl) {
      int mtg = wave * 2 + mtl;
      bf16x8 ar = *(const bf16x8*)&wsw_r[(size_t)((mtg * 4 + ks) * 64 + lane) * 8];
      bf16x8 al = *(const bf16x8*)&wsw_l[(size_t)((mtg * 4 + ks) * 64 + lane) * 8];
#pragma unroll
      for (int nt = 0; nt < 4; ++nt) {
        accr[mtl][nt] = __builtin_amdgcn_mfma_f32_16x16x32_bf16(ar, bfrag[nt], accr[mtl][nt], 0, 0, 0);
        accl[mtl][nt] = __builtin_amdgcn_mfma_f32_16x16x32_bf16(al, bfrag[nt], accl[mtl][nt], 0, 0, 0);
      }
    }
  }

  // ---- bias preloads: weight-col = (2w+mtl)*16 + 4q + r ----
  float4 brv[2], blv[2];
#pragma unroll
  for (int mtl = 0; mtl < 2; ++mtl) {
    int colb = (wave * 2 + mtl) * 16 + quad * 4;
    brv[mtl] = *(const float4*)&br[colb];
    blv[mtl] = *(const float4*)&bl[colb];
  }

  // ---- right epilogue: u[e, p=wave] = sum_c (right+br)*t ----
#pragma unroll
  for (int nt = 0; nt < 4; ++nt) {
    int e = nt * 16 + l16;
    ushort4 ta = *(const ushort4*)&t_s[e * 40 + 4 * quad];        // c: mtl=0
    ushort4 tb = *(const ushort4*)&t_s[e * 40 + 16 + 4 * quad];   // c: mtl=1
    float s = (accr[0][nt][0] + brv[0].x) * bf2f(ta.x)
            + (accr[0][nt][1] + brv[0].y) * bf2f(ta.y)
            + (accr[0][nt][2] + brv[0].z) * bf2f(ta.z)
            + (accr[0][nt][3] + brv[0].w) * bf2f(ta.w)
            + (accr[1][nt][0] + brv[1].x) * bf2f(tb.x)
            + (accr[1][nt][1] + brv[1].y) * bf2f(tb.y)
            + (accr[1][nt][2] + brv[1].z) * bf2f(tb.z)
            + (accr[1][nt][3] + brv[1].w) * bf2f(tb.w);
    s += __shfl_xor(s, 16);
    s += __shfl_xor(s, 32);
    if (quad == 0) u_s[e * 12 + wave] = s;
  }
  __syncthreads();   // u_s ready; efs reads long done -> t2_s overlay safe

  // ---- left epilogue: t2[e, r2] = sum_p (left+bl)*u ----
#pragma unroll
  for (int nt = 0; nt < 4; ++nt) {
    int e = nt * 16 + l16;
    float4 uv = *(const float4*)&u_s[e * 12 + 4 * (quad & 1)];
#pragma unroll
    for (int mtl = 0; mtl < 2; ++mtl) {
      float s = (accl[mtl][nt][0] + blv[mtl].x) * uv.x
              + (accl[mtl][nt][1] + blv[mtl].y) * uv.y
              + (accl[mtl][nt][2] + blv[mtl].z) * uv.z
              + (accl[mtl][nt][3] + blv[mtl].w) * uv.w;
      s += __shfl_xor(s, 16);                    // combine p halves (q^1)
      if ((quad & 1) == 0)
        t2_s[e * 36 + 4 * wave + 2 * mtl + (quad >> 1)] = s;
    }
  }
  __syncthreads();

  // ---- kv stage: thread -> (e = tid>>3, j = tid&7) => elements j*8..j*8+7 ----
  {
    int e = tid >> 3, j = tid & 7;
    float4 t2 = *(const float4*)&t2_s[e * 36 + 4 * j];   // r2 = 4j..4j+3
    float4 b2a = *(const float4*)&b2_s[e * 12 + 0];
    float4 b2b = *(const float4*)&b2_s[e * 12 + 4];
    unsigned q0 = pack_bf16(t2.x * b2a.x + t2.y * b2b.x, t2.x * b2a.y + t2.y * b2b.y);
    unsigned q1 = pack_bf16(t2.x * b2a.z + t2.y * b2b.z, t2.x * b2a.w + t2.y * b2b.w);
    unsigned q2 = pack_bf16(t2.z * b2a.x + t2.w * b2b.x, t2.z * b2a.y + t2.w * b2b.y);
    unsigned q3 = pack_bf16(t2.z * b2a.z + t2.w * b2b.z, t2.z * b2a.w + t2.w * b2b.w);
    *(uint4*)&kv[(i0 + e) * 64 + j * 8] = make_uint4(q0, q1, q2, q3);
  }
}

// ---------------- fused attention gather (streaming, DPP, unroll x2) --------
__global__ void __launch_bounds__(256) attn_gather_kernel(
    const float* __restrict__ q, const u16* __restrict__ kvk,
    const u16* __restrict__ kvv, const int* __restrict__ rowptr,
    float* __restrict__ outp) {
  int tid = threadIdx.x;
  int node = blockIdx.x * 4 + (tid >> 6);        // grid 2500 * 4 = NNODES
  int lane = tid & 63;
  float qv = q[(size_t)node * 64 + lane];
  int beg = rowptr[node], end = rowptr[node + 1];
  float num = 0.f, den = 0.f;
  int idx = beg;
  for (; idx + 2 <= end; idx += 2) {             // 2 independent chains
    float kf0 = bf2f(kvk[(size_t)idx * 64 + lane]);
    float kf1 = bf2f(kvk[(size_t)(idx + 1) * 64 + lane]);
    float v0  = bf2f(kvv[(size_t)idx * 64 + lane]);
    float v1  = bf2f(kvv[(size_t)(idx + 1) * 64 + lane]);
    float p0 = dpp_red16(qv * kf0);
    float p1 = dpp_red16(qv * kf1);
    float e0 = __expf(p0 * 0.25f);
    float e1 = __expf(p1 * 0.25f);
    den += e0 + e1;
    num += e0 * v0 + e1 * v1;
  }
  if (idx < end) {
    float kf = bf2f(kvk[(size_t)idx * 64 + lane]);
    float p = dpp_red16(qv * kf);
    float exv = __expf(p * 0.25f);
    den += exv;
    num += exv * bf2f(kvv[(size_t)idx * 64 + lane]);
  }
  outp[(size_t)node * 64 + lane] = num / fmaxf(den, 1e-9f);
}

extern "C" void kernel_launch(void* const* d_in, const int* in_sizes, int n_in,
                              void* d_out, int out_size, void* d_ws, size_t ws_size,
                              hipStream_t stream) {
  const float* b1  = (const float*)d_in[0];
  const float* b2  = (const float*)d_in[1];
  const float* ef  = (const float*)d_in[2];
  const float* f   = (const float*)d_in[3];
  const int*   src = (const int*)d_in[4];
  const int*   dst = (const int*)d_in[5];
  const float* qw  = (const float*)d_in[6];
  const float* qb  = (const float*)d_in[7];
  const float* kw1 = (const float*)d_in[8];
  const float* kb1 = (const float*)d_in[9];
  const float* kwl = (const float*)d_in[10];
  const float* kbl = (const float*)d_in[11];
  const float* kwr = (const float*)d_in[12];
  const float* kbr = (const float*)d_in[13];
  const float* vw1 = (const float*)d_in[14];
  const float* vb1 = (const float*)d_in[15];
  const float* vwl = (const float*)d_in[16];
  const float* vbl = (const float*)d_in[17];
  const float* vwr = (const float*)d_in[18];
  const float* vbr = (const float*)d_in[19];
  float* outp = (float*)d_out;

  // workspace layout
  char* ws = (char*)d_ws;
  size_t off = 0;
  auto alloc = [&](size_t bytes) {
    char* p = ws + off;
    off += (bytes + 511) & ~(size_t)511;
    return p;
  };
  u16*   Wsw  = (u16*)  alloc((size_t)4 * 32768 * 2);
  u16*   W1sw = (u16*)  alloc((size_t)2 * 4096 * 2);
  char*  comb = (char*) alloc((size_t)NEDGE * 192);
  u16*   kvk  = (u16*)  alloc((size_t)NEDGE * 64 * 2);
  u16*   kvv  = (u16*)  alloc((size_t)NEDGE * 64 * 2);
  float* qbuf = (float*)alloc((size_t)NNODES * 64 * 4);
  int*   cnt    = (int*)alloc((size_t)NNODES * 4);
  int*   rowptr = (int*)alloc((size_t)(NNODES + 1) * 4);
  int*   cursor = (int*)alloc((size_t)NNODES * 4);

  // zero counts (kernel, graph-capture-safe), then fused setup
  zero_cnt_kernel<<<40, 256, 0, stream>>>(cnt);
  setup_kernel<<<1794, 256, 0, stream>>>(kwr, kwl, vwr, vwl, Wsw,
                                         kw1, vw1, W1sw,
                                         f, qw, qb, qbuf, dst, cnt);
  csr_scan_kernel<<<1, 1024, 0, stream>>>(cnt, rowptr, cursor);
  fill_t_kernel<<<625, 256, 0, stream>>>(dst, src, f, b1, b2, ef,
                                         cursor, comb);

  // conv K
  conv_fused_kernel<<<2500, 512, 0, stream>>>(comb, W1sw + 0 * 4096, kb1,
                                              Wsw + 0 * 32768, kbr,
                                              Wsw + 1 * 32768, kbl,
                                              kvk);
  // conv V
  conv_fused_kernel<<<2500, 512, 0, stream>>>(comb, W1sw + 1 * 4096, vb1,
                                              Wsw + 2 * 32768, vbr,
                                              Wsw + 3 * 32768, vbl,
                                              kvv);

  // fused attention (streaming reads, DPP reductions, no atomics)
  attn_gather_kernel<<<2500, 256, 0, stream>>>(qbuf, kvk, kvv, rowptr, outp);
}

// Round 12
// 246.171 us; speedup vs baseline: 2.7234x; 1.0143x over previous
//
#include <hip/hip_runtime.h>
#include <hip/hip_bf16.h>
#include <math.h>

// Problem constants
#define NNODES 10000
#define NEDGE  160000
// MULT=16, NL=2, DIM=4, EDGE_DIM=32, HID=128, RANK=8, H=4, HM=4

typedef unsigned short u16;
using bf16x8 = __attribute__((ext_vector_type(8))) short;
using u16x8  = __attribute__((ext_vector_type(8))) unsigned short;
using f32x4  = __attribute__((ext_vector_type(4))) float;

static __device__ __forceinline__ u16 f2bf(float x) {
  unsigned u = __float_as_uint(x);
  u += 0x7FFFu + ((u >> 16) & 1u);     // RNE
  return (u16)(u >> 16);
}
static __device__ __forceinline__ float bf2f(u16 h) {
  return __uint_as_float(((unsigned)h) << 16);
}
// packed RNE f32x2 -> bf16x2 (gfx950 v_cvt_pk_bf16_f32 via HIP API)
static __device__ __forceinline__ unsigned pack_bf16(float a, float b) {
  __hip_bfloat162 h = __float22bfloat162_rn(make_float2(a, b));
  return *(unsigned*)&h;               // low = a, high = b
}
// tanh-form gelu: x*sigmoid(x*(1.5957691 + 0.0713548*x^2)); |err| < 5e-4 abs.
static __device__ __forceinline__ float fast_gelu(float x) {
  float y = x * __builtin_fmaf(0.07135481283f, x * x, 1.5957691216f);
  float e = __expf(y);
  return x - x * __builtin_amdgcn_rcpf(e + 1.0f);
}

// ---------------- zero cnt (must finish before setup's csr_count) -----------
__global__ void zero_cnt_kernel(int* __restrict__ cnt) {
  int i = blockIdx.x * 256 + threadIdx.x;
  if (i < NNODES) cnt[i] = 0;
}

// ---------------- fused setup: prep_w | prep_w1 | q | csr_count -------------
__global__ void __launch_bounds__(256) setup_kernel(
    const float* __restrict__ kwr, const float* __restrict__ kwl,
    const float* __restrict__ vwr, const float* __restrict__ vwl,
    u16* __restrict__ Wsw,
    const float* __restrict__ kw1, const float* __restrict__ vw1,
    u16* __restrict__ W1sw,
    const float* __restrict__ f, const float* __restrict__ qw,
    const float* __restrict__ qb, float* __restrict__ q,
    const int* __restrict__ dst, int* __restrict__ cnt) {
  int b = blockIdx.x, tid = threadIdx.x;
  if (b < 512) {                      // prep_w
    int idx = b * 256 + tid;          // 0..131071  (4 slots x 32768)
    int slot = idx >> 15;
    int w = idx & 32767;
    int j = w & 7, lane = (w >> 3) & 63, ks = (w >> 9) & 3, tg = w >> 11;
    int k   = ks * 32 + ((lane >> 4) << 3) + j;
    int col = (tg << 4) + (lane & 15);
    const float* s = (slot == 0) ? kwr : (slot == 1) ? kwl : (slot == 2) ? vwr : vwl;
    Wsw[idx] = f2bf(s[k * 256 + col]);
  } else if (b < 544) {               // prep_w1
    int idx = (b - 512) * 256 + tid;  // 0..8191 (2 slots x 4096)
    int slot = idx >> 12;
    int w = idx & 4095;
    int j = w & 7, lane = (w >> 3) & 63, nt = w >> 9;
    int k   = ((lane >> 4) << 3) + j;
    int col = (nt << 4) + (lane & 15);
    const float* s = (slot == 0) ? kw1 : vw1;
    W1sw[idx] = f2bf(s[k * 128 + col]);
  } else if (b < 1169) {              // q: 625 blocks
    int i = (b - 544) * 256 + tid;    // n*16 + o
    if (i >= NNODES * 16) return;
    int n = i >> 4, o = i & 15;
    const float* frow = f + (size_t)n * 64;
    float o0 = 0.f, o1 = 0.f, o2 = 0.f, o3 = 0.f;
#pragma unroll
    for (int m = 0; m < 16; ++m) {
      float w0 = qw[o * 16 + m];
      float w1 = qw[(16 + o) * 16 + m];
      o0 += w0 * frow[m * 4 + 0];
      o1 += w1 * frow[m * 4 + 1];
      o2 += w1 * frow[m * 4 + 2];
      o3 += w1 * frow[m * 4 + 3];
    }
    o0 += qb[o];
    float4 r = make_float4(o0, o1, o2, o3);
    *(float4*)(q + (size_t)i * 4) = r;
  } else {                            // csr_count: 625 blocks
    int e = (b - 1169) * 256 + tid;   // exact
    atomicAdd(&cnt[dst[e]], 1);
  }
}

// ---------------- CSR scan ---------------------------------------------------
__global__ void __launch_bounds__(1024) csr_scan_kernel(
    const int* __restrict__ cnt, int* __restrict__ rowptr, int* __restrict__ cursor) {
  __shared__ int part[1024];
  int t = threadIdx.x;
  int base = t * 10;                              // 1024*10 = 10240 >= NNODES
  int s = 0;
#pragma unroll
  for (int i = 0; i < 10; ++i) { int idx = base + i; if (idx < NNODES) s += cnt[idx]; }
  part[t] = s;
  __syncthreads();
  for (int o = 1; o < 1024; o <<= 1) {
    int v = (t >= o) ? part[t - o] : 0;
    __syncthreads();
    part[t] += v;
    __syncthreads();
  }
  int run = (t == 0) ? 0 : part[t - 1];
#pragma unroll
  for (int i = 0; i < 10; ++i) {
    int idx = base + i;
    if (idx < NNODES) { rowptr[idx] = run; cursor[idx] = run; run += cnt[idx]; }
  }
  if (t == 1023) rowptr[NNODES] = run;
}

// ---------------- fill: t | ef(bf16) | b2 | dstn into 192B/edge record ------
// Record (pos-ordered): [t: 32 u16][ef: 32 u16][b2: 8 f32][n: i32] = 164B,
// pitch 192B = 3 full 64B lines -> no partial-sector RMW on scattered writes.
__global__ void __launch_bounds__(256) fill_t_kernel(
    const int* __restrict__ dst, const int* __restrict__ src,
    const float* __restrict__ f, const float* __restrict__ b1,
    const float* __restrict__ b2, const float* __restrict__ ef,
    int* __restrict__ cursor, char* __restrict__ comb) {
  int e = blockIdx.x * 256 + threadIdx.x;        // grid exact
  int n = dst[e];
  int pos = atomicAdd(&cursor[n], 1);
  char* rb = comb + (size_t)pos * 192;
  // t row: t[m,l] = sum_d f[src][m][d] * b1[e][d][l]
  const float* frow = f + (size_t)src[e] * 64;
  const float* be = b1 + (size_t)e * 8;          // (4,2)
  float b[8];
#pragma unroll
  for (int k = 0; k < 8; ++k) b[k] = be[k];
  uint4* tp = (uint4*)rb;
#pragma unroll
  for (int mh = 0; mh < 4; ++mh) {
    unsigned pk[4];
#pragma unroll
    for (int mi = 0; mi < 4; ++mi) {
      int m = mh * 4 + mi;
      float f0 = frow[m * 4 + 0], f1 = frow[m * 4 + 1], f2 = frow[m * 4 + 2], f3 = frow[m * 4 + 3];
      float t0 = f0 * b[0] + f1 * b[2] + f2 * b[4] + f3 * b[6];
      float t1 = f0 * b[1] + f1 * b[3] + f2 * b[5] + f3 * b[7];
      pk[mi] = pack_bf16(t0, t1);
    }
    tp[mh] = make_uint4(pk[0], pk[1], pk[2], pk[3]);
  }
  // ef bf16 cast at +64B
  const float* efe = ef + (size_t)e * 32;
#pragma unroll
  for (int g = 0; g < 4; ++g) {
    float4 v0 = *(const float4*)&efe[g * 8];
    float4 v1 = *(const float4*)&efe[g * 8 + 4];
    tp[4 + g] = make_uint4(pack_bf16(v0.x, v0.y), pack_bf16(v0.z, v0.w),
                           pack_bf16(v1.x, v1.y), pack_bf16(v1.z, v1.w));
  }
  // b2 copy at +128B, dst node at +160B
  const float* b2e = b2 + (size_t)e * 8;
  *(float4*)(rb + 128) = *(const float4*)&b2e[0];
  *(float4*)(rb + 144) = *(const float4*)&b2e[4];
  *(int*)(rb + 160) = n;
}

// ---------------- fused equivariant conv (transposed GEMMs) -----------------
// exs != null (K mode): final stage computes attention scores ex=exp(qk/4)
//   from fp32 kv values in-register -> writes E x 4 floats (no kvk matrix!).
// kv != null (V mode): packs bf16 kv rows as before.
// NO min-wave launch bound: acc floor is 64 VGPRs (16x f32x4); forcing
// 8 waves/EU (round 8/9) spilled 814 MB scratch and ran 254+ us.
__global__ void __launch_bounds__(512) conv_fused_kernel(
    const char* __restrict__ comb, const u16* __restrict__ w1sw,
    const float* __restrict__ b1h,
    const u16* __restrict__ wsw_r, const float* __restrict__ br,
    const u16* __restrict__ wsw_l, const float* __restrict__ bl,
    const float* __restrict__ qbuf, float* __restrict__ exs,
    u16* __restrict__ kv) {
  __shared__ alignas(16) u16 sA[64 * 136];    // H tile [edge][hid]
  __shared__ alignas(16) u16 t_s[64 * 40];    // t tile (bf16)
  __shared__ alignas(16) float b2_s[64 * 12];
  __shared__ alignas(16) float u_s[64 * 12];  // u[e][p]
  __shared__ alignas(16) float t2_pool[64 * 36]; // t2[e][r2]; overlays efs
  float* t2_s = t2_pool;
  u16*   efs  = (u16*)t2_pool;                // ef tile bf16 [edge][k] pitch 40

  int tid = threadIdx.x;
  int wave = tid >> 6, lane = tid & 63, quad = lane >> 4, l16 = lane & 15;
  size_t i0 = (size_t)blockIdx.x * 64;

  // ---- stage tiles from comb ----
  if (tid < 256) {            // ef tile: 64 rows x 64B at +64
    int row = tid >> 2, seg = tid & 3;
    *(uint4*)&efs[row * 40 + seg * 8] =
        *(const uint4*)(comb + (i0 + row) * 192 + 64 + seg * 16);
    if (tid < 128) {          // b2 tile: 64 rows x 32B at +128
      int r2 = tid >> 1, half = tid & 1;
      *(float4*)&b2_s[r2 * 12 + half * 4] =
          *(const float4*)(comb + (i0 + r2) * 192 + 128 + half * 16);
    }
  } else {                    // t tile: 64 rows x 64B at +0
    int j = tid - 256;
    int row = j >> 2, seg = j & 3;
    *(uint4*)&t_s[row * 40 + seg * 8] =
        *(const uint4*)(comb + (i0 + row) * 192 + seg * 16);
  }
  __syncthreads();

  // ---- h-stage: wave owns hid-tile `wave` (16 cols), 4 edge tiles ----
  {
    bf16x8 aw = *(const bf16x8*)&w1sw[(size_t)(wave * 64 + lane) * 8];  // A = w1^T
    float4 bias_h = *(const float4*)&b1h[wave * 16 + quad * 4];
#pragma unroll
    for (int nt = 0; nt < 4; ++nt) {
      bf16x8 be = *(const bf16x8*)&efs[(nt * 16 + l16) * 40 + quad * 8]; // B = ef^T
      f32x4 acch = __builtin_amdgcn_mfma_f32_16x16x32_bf16(aw, be, (f32x4){0.f, 0.f, 0.f, 0.f}, 0, 0, 0);
      unsigned p0 = pack_bf16(fast_gelu(acch[0] + bias_h.x), fast_gelu(acch[1] + bias_h.y));
      unsigned p1 = pack_bf16(fast_gelu(acch[2] + bias_h.z), fast_gelu(acch[3] + bias_h.w));
      *(uint2*)&sA[(nt * 16 + l16) * 136 + wave * 16 + quad * 4] = make_uint2(p0, p1);
    }
  }
  __syncthreads();

  // ---- K-loop: transposed GEMMs (A = weights, B = H), zero-seeded accs ----
  f32x4 accr[2][4], accl[2][4];
#pragma unroll
  for (int mtl = 0; mtl < 2; ++mtl)
#pragma unroll
    for (int nt = 0; nt < 4; ++nt) {
      accr[mtl][nt] = (f32x4){0.f, 0.f, 0.f, 0.f};
      accl[mtl][nt] = (f32x4){0.f, 0.f, 0.f, 0.f};
    }
#pragma unroll
  for (int ks = 0; ks < 4; ++ks) {
    bf16x8 bfrag[4];
#pragma unroll
    for (int nt = 0; nt < 4; ++nt)
      bfrag[nt] = *(const bf16x8*)&sA[(nt * 16 + l16) * 136 + ks * 32 + quad * 8];
#pragma unroll
    for (int mtl = 0; mtl < 2; ++mtl) {
      int mtg = wave * 2 + mtl;
      bf16x8 ar = *(const bf16x8*)&wsw_r[(size_t)((mtg * 4 + ks) * 64 + lane) * 8];
      bf16x8 al = *(const bf16x8*)&wsw_l[(size_t)((mtg * 4 + ks) * 64 + lane) * 8];
#pragma unroll
      for (int nt = 0; nt < 4; ++nt) {
        accr[mtl][nt] = __builtin_amdgcn_mfma_f32_16x16x32_bf16(ar, bfrag[nt], accr[mtl][nt], 0, 0, 0);
        accl[mtl][nt] = __builtin_amdgcn_mfma_f32_16x16x32_bf16(al, bfrag[nt], accl[mtl][nt], 0, 0, 0);
      }
    }
  }

  // ---- bias preloads: weight-col = (2w+mtl)*16 + 4q + r ----
  float4 brv[2], blv[2];
#pragma unroll
  for (int mtl = 0; mtl < 2; ++mtl) {
    int colb = (wave * 2 + mtl) * 16 + quad * 4;
    brv[mtl] = *(const float4*)&br[colb];
    blv[mtl] = *(const float4*)&bl[colb];
  }

  // ---- right epilogue: u[e, p=wave] = sum_c (right+br)*t ----
#pragma unroll
  for (int nt = 0; nt < 4; ++nt) {
    int e = nt * 16 + l16;
    ushort4 ta = *(const ushort4*)&t_s[e * 40 + 4 * quad];        // c: mtl=0
    ushort4 tb = *(const ushort4*)&t_s[e * 40 + 16 + 4 * quad];   // c: mtl=1
    float s = (accr[0][nt][0] + brv[0].x) * bf2f(ta.x)
            + (accr[0][nt][1] + brv[0].y) * bf2f(ta.y)
            + (accr[0][nt][2] + brv[0].z) * bf2f(ta.z)
            + (accr[0][nt][3] + brv[0].w) * bf2f(ta.w)
            + (accr[1][nt][0] + brv[1].x) * bf2f(tb.x)
            + (accr[1][nt][1] + brv[1].y) * bf2f(tb.y)
            + (accr[1][nt][2] + brv[1].z) * bf2f(tb.z)
            + (accr[1][nt][3] + brv[1].w) * bf2f(tb.w);
    s += __shfl_xor(s, 16);
    s += __shfl_xor(s, 32);
    if (quad == 0) u_s[e * 12 + wave] = s;
  }
  __syncthreads();   // u_s ready; efs reads long done -> t2_s overlay safe

  // ---- left epilogue: t2[e, r2] = sum_p (left+bl)*u ----
#pragma unroll
  for (int nt = 0; nt < 4; ++nt) {
    int e = nt * 16 + l16;
    float4 uv = *(const float4*)&u_s[e * 12 + 4 * (quad & 1)];
#pragma unroll
    for (int mtl = 0; mtl < 2; ++mtl) {
      float s = (accl[mtl][nt][0] + blv[mtl].x) * uv.x
              + (accl[mtl][nt][1] + blv[mtl].y) * uv.y
              + (accl[mtl][nt][2] + blv[mtl].z) * uv.z
              + (accl[mtl][nt][3] + blv[mtl].w) * uv.w;
      s += __shfl_xor(s, 16);                    // combine p halves (q^1)
      if ((quad & 1) == 0)
        t2_s[e * 36 + 4 * wave + 2 * mtl + (quad >> 1)] = s;
    }
  }
  __syncthreads();

  // ---- final stage: thread -> (e = tid>>3, j = tid&7), elems j*8..j*8+7 ----
  {
    int e = tid >> 3, j = tid & 7;
    float4 t2 = *(const float4*)&t2_s[e * 36 + 4 * j];   // r2 = 4j..4j+3
    float4 b2a = *(const float4*)&b2_s[e * 12 + 0];
    float4 b2b = *(const float4*)&b2_s[e * 12 + 4];
    float v0 = t2.x * b2a.x + t2.y * b2b.x;   // m=2j,   d=0..3
    float v1 = t2.x * b2a.y + t2.y * b2b.y;
    float v2 = t2.x * b2a.z + t2.y * b2b.z;
    float v3 = t2.x * b2a.w + t2.y * b2b.w;
    float v4 = t2.z * b2a.x + t2.w * b2b.x;   // m=2j+1, d=0..3
    float v5 = t2.z * b2a.y + t2.w * b2b.y;
    float v6 = t2.z * b2a.z + t2.w * b2b.z;
    float v7 = t2.z * b2a.w + t2.w * b2b.w;
    if (exs) {
      // K mode: head (j>>1) half-dot with q, pair-combine, exp, store ex
      int n = *(const int*)(comb + (i0 + e) * 192 + 160);
      const float* qr = qbuf + (size_t)n * 64 + j * 8;
      float4 qa = *(const float4*)&qr[0];
      float4 qc = *(const float4*)&qr[4];
      float s = v0 * qa.x + v1 * qa.y + v2 * qa.z + v3 * qa.w
              + v4 * qc.x + v5 * qc.y + v6 * qc.z + v7 * qc.w;
      s += __shfl_xor(s, 1);                     // combine the two half-heads
      if ((j & 1) == 0)
        exs[(i0 + e) * 4 + (j >> 1)] = __expf(s * 0.25f);
    } else {
      // V mode: pack bf16 kv row
      unsigned q0 = pack_bf16(v0, v1);
      unsigned q1 = pack_bf16(v2, v3);
      unsigned q2 = pack_bf16(v4, v5);
      unsigned q3 = pack_bf16(v6, v7);
      *(uint4*)&kv[(i0 + e) * 64 + j * 8] = make_uint4(q0, q1, q2, q3);
    }
  }
}

// ---------------- attention gather: pure streaming weighted sum -------------
// ex precomputed by conv-K; per edge: num += ex*v, den += ex. No shuffles/exp.
__global__ void __launch_bounds__(256) attn_gather_kernel(
    const float* __restrict__ exs, const u16* __restrict__ kvv,
    const int* __restrict__ rowptr, float* __restrict__ outp) {
  int tid = threadIdx.x;
  int node = blockIdx.x * 4 + (tid >> 6);        // grid 2500 * 4 = NNODES
  int lane = tid & 63, h = lane >> 4;
  int beg = rowptr[node], end = rowptr[node + 1];
  float num = 0.f, den = 0.f;
  int idx = beg;
  for (; idx + 2 <= end; idx += 2) {
    float e0 = exs[(size_t)idx * 4 + h];
    float e1 = exs[(size_t)(idx + 1) * 4 + h];
    float v0 = bf2f(kvv[(size_t)idx * 64 + lane]);
    float v1 = bf2f(kvv[(size_t)(idx + 1) * 64 + lane]);
    num += e0 * v0 + e1 * v1;
    den += e0 + e1;
  }
  if (idx < end) {
    float e0 = exs[(size_t)idx * 4 + h];
    num += e0 * bf2f(kvv[(size_t)idx * 64 + lane]);
    den += e0;
  }
  outp[(size_t)node * 64 + lane] = num / fmaxf(den, 1e-9f);
}

extern "C" void kernel_launch(void* const* d_in, const int* in_sizes, int n_in,
                              void* d_out, int out_size, void* d_ws, size_t ws_size,
                              hipStream_t stream) {
  const float* b1  = (const float*)d_in[0];
  const float* b2  = (const float*)d_in[1];
  const float* ef  = (const float*)d_in[2];
  const float* f   = (const float*)d_in[3];
  const int*   src = (const int*)d_in[4];
  const int*   dst = (const int*)d_in[5];
  const float* qw  = (const float*)d_in[6];
  const float* qb  = (const float*)d_in[7];
  const float* kw1 = (const float*)d_in[8];
  const float* kb1 = (const float*)d_in[9];
  const float* kwl = (const float*)d_in[10];
  const float* kbl = (const float*)d_in[11];
  const float* kwr = (const float*)d_in[12];
  const float* kbr = (const float*)d_in[13];
  const float* vw1 = (const float*)d_in[14];
  const float* vb1 = (const float*)d_in[15];
  const float* vwl = (const float*)d_in[16];
  const float* vbl = (const float*)d_in[17];
  const float* vwr = (const float*)d_in[18];
  const float* vbr = (const float*)d_in[19];
  float* outp = (float*)d_out;

  // workspace layout
  char* ws = (char*)d_ws;
  size_t off = 0;
  auto alloc = [&](size_t bytes) {
    char* p = ws + off;
    off += (bytes + 511) & ~(size_t)511;
    return p;
  };
  u16*   Wsw  = (u16*)  alloc((size_t)4 * 32768 * 2);
  u16*   W1sw = (u16*)  alloc((size_t)2 * 4096 * 2);
  char*  comb = (char*) alloc((size_t)NEDGE * 192);
  u16*   kvv  = (u16*)  alloc((size_t)NEDGE * 64 * 2);
  float* exb  = (float*)alloc((size_t)NEDGE * 4 * 4);
  float* qbuf = (float*)alloc((size_t)NNODES * 64 * 4);
  int*   cnt    = (int*)alloc((size_t)NNODES * 4);
  int*   rowptr = (int*)alloc((size_t)(NNODES + 1) * 4);
  int*   cursor = (int*)alloc((size_t)NNODES * 4);

  // zero counts (kernel, graph-capture-safe), then fused setup
  zero_cnt_kernel<<<40, 256, 0, stream>>>(cnt);
  setup_kernel<<<1794, 256, 0, stream>>>(kwr, kwl, vwr, vwl, Wsw,
                                         kw1, vw1, W1sw,
                                         f, qw, qb, qbuf, dst, cnt);
  csr_scan_kernel<<<1, 1024, 0, stream>>>(cnt, rowptr, cursor);
  fill_t_kernel<<<625, 256, 0, stream>>>(dst, src, f, b1, b2, ef,
                                         cursor, comb);

  // conv K: emits attention ex weights directly (no kvk matrix)
  conv_fused_kernel<<<2500, 512, 0, stream>>>(comb, W1sw + 0 * 4096, kb1,
                                              Wsw + 0 * 32768, kbr,
                                              Wsw + 1 * 32768, kbl,
                                              qbuf, exb, nullptr);
  // conv V: emits bf16 value rows
  conv_fused_kernel<<<2500, 512, 0, stream>>>(comb, W1sw + 1 * 4096, vb1,
                                              Wsw + 2 * 32768, vbr,
                                              Wsw + 3 * 32768, vbl,
                                              qbuf, nullptr, kvv);

  // attention: pure streaming weighted sum
  attn_gather_kernel<<<2500, 256, 0, stream>>>(exb, kvv, rowptr, outp);
}

// Round 13
// 245.818 us; speedup vs baseline: 2.7273x; 1.0014x over previous
//
#include <hip/hip_runtime.h>
#include <hip/hip_bf16.h>
#include <math.h>

// Problem constants
#define NNODES 10000
#define NEDGE  160000
// MULT=16, NL=2, DIM=4, EDGE_DIM=32, HID=128, RANK=8, H=4, HM=4

typedef unsigned short u16;
using bf16x8 = __attribute__((ext_vector_type(8))) short;
using u16x8  = __attribute__((ext_vector_type(8))) unsigned short;
using f32x4  = __attribute__((ext_vector_type(4))) float;

static __device__ __forceinline__ u16 f2bf(float x) {
  unsigned u = __float_as_uint(x);
  u += 0x7FFFu + ((u >> 16) & 1u);     // RNE
  return (u16)(u >> 16);
}
static __device__ __forceinline__ float bf2f(u16 h) {
  return __uint_as_float(((unsigned)h) << 16);
}
// packed RNE f32x2 -> bf16x2 (gfx950 v_cvt_pk_bf16_f32 via HIP API)
static __device__ __forceinline__ unsigned pack_bf16(float a, float b) {
  __hip_bfloat162 h = __float22bfloat162_rn(make_float2(a, b));
  return *(unsigned*)&h;               // low = a, high = b
}
// tanh-form gelu: x*sigmoid(x*(1.5957691 + 0.0713548*x^2)); |err| < 5e-4 abs.
static __device__ __forceinline__ float fast_gelu(float x) {
  float y = x * __builtin_fmaf(0.07135481283f, x * x, 1.5957691216f);
  float e = __expf(y);
  return x - x * __builtin_amdgcn_rcpf(e + 1.0f);
}

// ---------------- CSR build: histogram + scan in ONE single-block kernel -----
// Replaces zero_cnt + csr_count + csr_scan (2 fewer dispatches; ~10-15us each
// of graph-node overhead per the round-12 budget audit).
__global__ void __launch_bounds__(1024) csr_build_kernel(
    const int* __restrict__ dst, int* __restrict__ rowptr, int* __restrict__ cursor) {
  __shared__ int hist[NNODES];       // 40000 B
  __shared__ int part[1024];         //  4096 B
  int t = threadIdx.x;
  for (int i = t; i < NNODES; i += 1024) hist[i] = 0;
  __syncthreads();
  const int4* d4 = (const int4*)dst; // NEDGE/4 = 40000 int4s, coalesced
  for (int i = t; i < NEDGE / 4; i += 1024) {
    int4 v = d4[i];
    atomicAdd(&hist[v.x], 1);
    atomicAdd(&hist[v.y], 1);
    atomicAdd(&hist[v.z], 1);
    atomicAdd(&hist[v.w], 1);
  }
  __syncthreads();
  int base = t * 10;                 // 1024*10 = 10240 >= NNODES
  int local[10];
  int s = 0;
#pragma unroll
  for (int i = 0; i < 10; ++i) {
    int idx = base + i;
    local[i] = (idx < NNODES) ? hist[idx] : 0;
    s += local[i];
  }
  part[t] = s;
  __syncthreads();
  for (int o = 1; o < 1024; o <<= 1) {
    int v = (t >= o) ? part[t - o] : 0;
    __syncthreads();
    part[t] += v;
    __syncthreads();
  }
  int run = (t == 0) ? 0 : part[t - 1];
#pragma unroll
  for (int i = 0; i < 10; ++i) {
    int idx = base + i;
    if (idx < NNODES) { rowptr[idx] = run; cursor[idx] = run; run += local[i]; }
  }
  if (t == 1023) rowptr[NNODES] = run;
}

// ---------------- fused setup: prep_w | prep_w1 | q --------------------------
__global__ void __launch_bounds__(256) setup_kernel(
    const float* __restrict__ kwr, const float* __restrict__ kwl,
    const float* __restrict__ vwr, const float* __restrict__ vwl,
    u16* __restrict__ Wsw,
    const float* __restrict__ kw1, const float* __restrict__ vw1,
    u16* __restrict__ W1sw,
    const float* __restrict__ f, const float* __restrict__ qw,
    const float* __restrict__ qb, float* __restrict__ q) {
  int b = blockIdx.x, tid = threadIdx.x;
  if (b < 512) {                      // prep_w
    int idx = b * 256 + tid;          // 0..131071  (4 slots x 32768)
    int slot = idx >> 15;
    int w = idx & 32767;
    int j = w & 7, lane = (w >> 3) & 63, ks = (w >> 9) & 3, tg = w >> 11;
    int k   = ks * 32 + ((lane >> 4) << 3) + j;
    int col = (tg << 4) + (lane & 15);
    const float* s = (slot == 0) ? kwr : (slot == 1) ? kwl : (slot == 2) ? vwr : vwl;
    Wsw[idx] = f2bf(s[k * 256 + col]);
  } else if (b < 544) {               // prep_w1
    int idx = (b - 512) * 256 + tid;  // 0..8191 (2 slots x 4096)
    int slot = idx >> 12;
    int w = idx & 4095;
    int j = w & 7, lane = (w >> 3) & 63, nt = w >> 9;
    int k   = ((lane >> 4) << 3) + j;
    int col = (nt << 4) + (lane & 15);
    const float* s = (slot == 0) ? kw1 : vw1;
    W1sw[idx] = f2bf(s[k * 128 + col]);
  } else {                            // q: 625 blocks
    int i = (b - 544) * 256 + tid;    // n*16 + o
    if (i >= NNODES * 16) return;
    int n = i >> 4, o = i & 15;
    const float* frow = f + (size_t)n * 64;
    float o0 = 0.f, o1 = 0.f, o2 = 0.f, o3 = 0.f;
#pragma unroll
    for (int m = 0; m < 16; ++m) {
      float w0 = qw[o * 16 + m];
      float w1 = qw[(16 + o) * 16 + m];
      o0 += w0 * frow[m * 4 + 0];
      o1 += w1 * frow[m * 4 + 1];
      o2 += w1 * frow[m * 4 + 2];
      o3 += w1 * frow[m * 4 + 3];
    }
    o0 += qb[o];
    float4 r = make_float4(o0, o1, o2, o3);
    *(float4*)(q + (size_t)i * 4) = r;
  }
}

// ---------------- fill: t | ef(bf16) | b2 | dstn into 192B/edge record ------
// Record (pos-ordered): [t: 32 u16][ef: 32 u16][b2: 8 f32][n: i32] = 164B,
// pitch 192B = 3 full 64B lines -> no partial-sector RMW on scattered writes.
__global__ void __launch_bounds__(256) fill_t_kernel(
    const int* __restrict__ dst, const int* __restrict__ src,
    const float* __restrict__ f, const float* __restrict__ b1,
    const float* __restrict__ b2, const float* __restrict__ ef,
    int* __restrict__ cursor, char* __restrict__ comb) {
  int e = blockIdx.x * 256 + threadIdx.x;        // grid exact
  int n = dst[e];
  int pos = atomicAdd(&cursor[n], 1);
  char* rb = comb + (size_t)pos * 192;
  // t row: t[m,l] = sum_d f[src][m][d] * b1[e][d][l]
  const float* frow = f + (size_t)src[e] * 64;
  const float* be = b1 + (size_t)e * 8;          // (4,2)
  float b[8];
#pragma unroll
  for (int k = 0; k < 8; ++k) b[k] = be[k];
  uint4* tp = (uint4*)rb;
#pragma unroll
  for (int mh = 0; mh < 4; ++mh) {
    unsigned pk[4];
#pragma unroll
    for (int mi = 0; mi < 4; ++mi) {
      int m = mh * 4 + mi;
      float f0 = frow[m * 4 + 0], f1 = frow[m * 4 + 1], f2 = frow[m * 4 + 2], f3 = frow[m * 4 + 3];
      float t0 = f0 * b[0] + f1 * b[2] + f2 * b[4] + f3 * b[6];
      float t1 = f0 * b[1] + f1 * b[3] + f2 * b[5] + f3 * b[7];
      pk[mi] = pack_bf16(t0, t1);
    }
    tp[mh] = make_uint4(pk[0], pk[1], pk[2], pk[3]);
  }
  // ef bf16 cast at +64B
  const float* efe = ef + (size_t)e * 32;
#pragma unroll
  for (int g = 0; g < 4; ++g) {
    float4 v0 = *(const float4*)&efe[g * 8];
    float4 v1 = *(const float4*)&efe[g * 8 + 4];
    tp[4 + g] = make_uint4(pack_bf16(v0.x, v0.y), pack_bf16(v0.z, v0.w),
                           pack_bf16(v1.x, v1.y), pack_bf16(v1.z, v1.w));
  }
  // b2 copy at +128B, dst node at +160B
  const float* b2e = b2 + (size_t)e * 8;
  *(float4*)(rb + 128) = *(const float4*)&b2e[0];
  *(float4*)(rb + 144) = *(const float4*)&b2e[4];
  *(int*)(rb + 160) = n;
}

// ---------------- merged equivariant conv (K and V in one dispatch) ---------
// blockIdx even -> K conv for tile (blockIdx>>1): emits ex=exp(qk/4);
// blockIdx odd  -> V conv for same tile: emits bf16 kv rows.
// Adjacent K/V pairs read the same comb slice -> L2 reuse.
// Body identical to the validated 64-VGPR round-12 kernel (pointer selects
// are SGPR-only). NO min-wave launch bound (round 8/9: acc floor is 64 VGPRs;
// forcing 8 waves/EU spilled 814 MB scratch).
__global__ void __launch_bounds__(512) conv_fused_kernel(
    const char* __restrict__ comb,
    const u16* __restrict__ w1sw_k, const float* __restrict__ b1h_k,
    const u16* __restrict__ wswr_k, const float* __restrict__ br_k,
    const u16* __restrict__ wswl_k, const float* __restrict__ bl_k,
    const u16* __restrict__ w1sw_v, const float* __restrict__ b1h_v,
    const u16* __restrict__ wswr_v, const float* __restrict__ br_v,
    const u16* __restrict__ wswl_v, const float* __restrict__ bl_v,
    const float* __restrict__ qbuf, float* __restrict__ exs,
    u16* __restrict__ kv) {
  __shared__ alignas(16) u16 sA[64 * 136];    // H tile [edge][hid]
  __shared__ alignas(16) u16 t_s[64 * 40];    // t tile (bf16)
  __shared__ alignas(16) float b2_s[64 * 12];
  __shared__ alignas(16) float u_s[64 * 12];  // u[e][p]
  __shared__ alignas(16) float t2_pool[64 * 36]; // t2[e][r2]; overlays efs
  float* t2_s = t2_pool;
  u16*   efs  = (u16*)t2_pool;                // ef tile bf16 [edge][k] pitch 40

  int tid = threadIdx.x;
  int wave = tid >> 6, lane = tid & 63, quad = lane >> 4, l16 = lane & 15;
  bool kmode = (blockIdx.x & 1) == 0;
  size_t i0 = (size_t)(blockIdx.x >> 1) * 64;

  const u16*   w1sw = kmode ? w1sw_k : w1sw_v;
  const float* b1h  = kmode ? b1h_k  : b1h_v;
  const u16*   wsw_r = kmode ? wswr_k : wswr_v;
  const float* br    = kmode ? br_k   : br_v;
  const u16*   wsw_l = kmode ? wswl_k : wswl_v;
  const float* bl    = kmode ? bl_k   : bl_v;

  // ---- stage tiles from comb ----
  if (tid < 256) {            // ef tile: 64 rows x 64B at +64
    int row = tid >> 2, seg = tid & 3;
    *(uint4*)&efs[row * 40 + seg * 8] =
        *(const uint4*)(comb + (i0 + row) * 192 + 64 + seg * 16);
    if (tid < 128) {          // b2 tile: 64 rows x 32B at +128
      int r2 = tid >> 1, half = tid & 1;
      *(float4*)&b2_s[r2 * 12 + half * 4] =
          *(const float4*)(comb + (i0 + r2) * 192 + 128 + half * 16);
    }
  } else {                    // t tile: 64 rows x 64B at +0
    int j = tid - 256;
    int row = j >> 2, seg = j & 3;
    *(uint4*)&t_s[row * 40 + seg * 8] =
        *(const uint4*)(comb + (i0 + row) * 192 + seg * 16);
  }
  __syncthreads();

  // ---- h-stage: wave owns hid-tile `wave` (16 cols), 4 edge tiles ----
  {
    bf16x8 aw = *(const bf16x8*)&w1sw[(size_t)(wave * 64 + lane) * 8];  // A = w1^T
    float4 bias_h = *(const float4*)&b1h[wave * 16 + quad * 4];
#pragma unroll
    for (int nt = 0; nt < 4; ++nt) {
      bf16x8 be = *(const bf16x8*)&efs[(nt * 16 + l16) * 40 + quad * 8]; // B = ef^T
      f32x4 acch = __builtin_amdgcn_mfma_f32_16x16x32_bf16(aw, be, (f32x4){0.f, 0.f, 0.f, 0.f}, 0, 0, 0);
      unsigned p0 = pack_bf16(fast_gelu(acch[0] + bias_h.x), fast_gelu(acch[1] + bias_h.y));
      unsigned p1 = pack_bf16(fast_gelu(acch[2] + bias_h.z), fast_gelu(acch[3] + bias_h.w));
      *(uint2*)&sA[(nt * 16 + l16) * 136 + wave * 16 + quad * 4] = make_uint2(p0, p1);
    }
  }
  __syncthreads();

  // ---- K-loop: transposed GEMMs (A = weights, B = H), zero-seeded accs ----
  f32x4 accr[2][4], accl[2][4];
#pragma unroll
  for (int mtl = 0; mtl < 2; ++mtl)
#pragma unroll
    for (int nt = 0; nt < 4; ++nt) {
      accr[mtl][nt] = (f32x4){0.f, 0.f, 0.f, 0.f};
      accl[mtl][nt] = (f32x4){0.f, 0.f, 0.f, 0.f};
    }
#pragma unroll
  for (int ks = 0; ks < 4; ++ks) {
    bf16x8 bfrag[4];
#pragma unroll
    for (int nt = 0; nt < 4; ++nt)
      bfrag[nt] = *(const bf16x8*)&sA[(nt * 16 + l16) * 136 + ks * 32 + quad * 8];
#pragma unroll
    for (int mtl = 0; mtl < 2; ++mtl) {
      int mtg = wave * 2 + mtl;
      bf16x8 ar = *(const bf16x8*)&wsw_r[(size_t)((mtg * 4 + ks) * 64 + lane) * 8];
      bf16x8 al = *(const bf16x8*)&wsw_l[(size_t)((mtg * 4 + ks) * 64 + lane) * 8];
#pragma unroll
      for (int nt = 0; nt < 4; ++nt) {
        accr[mtl][nt] = __builtin_amdgcn_mfma_f32_16x16x32_bf16(ar, bfrag[nt], accr[mtl][nt], 0, 0, 0);
        accl[mtl][nt] = __builtin_amdgcn_mfma_f32_16x16x32_bf16(al, bfrag[nt], accl[mtl][nt], 0, 0, 0);
      }
    }
  }

  // ---- bias preloads: weight-col = (2w+mtl)*16 + 4q + r ----
  float4 brv[2], blv[2];
#pragma unroll
  for (int mtl = 0; mtl < 2; ++mtl) {
    int colb = (wave * 2 + mtl) * 16 + quad * 4;
    brv[mtl] = *(const float4*)&br[colb];
    blv[mtl] = *(const float4*)&bl[colb];
  }

  // ---- right epilogue: u[e, p=wave] = sum_c (right+br)*t ----
#pragma unroll
  for (int nt = 0; nt < 4; ++nt) {
    int e = nt * 16 + l16;
    ushort4 ta = *(const ushort4*)&t_s[e * 40 + 4 * quad];        // c: mtl=0
    ushort4 tb = *(const ushort4*)&t_s[e * 40 + 16 + 4 * quad];   // c: mtl=1
    float s = (accr[0][nt][0] + brv[0].x) * bf2f(ta.x)
            + (accr[0][nt][1] + brv[0].y) * bf2f(ta.y)
            + (accr[0][nt][2] + brv[0].z) * bf2f(ta.z)
            + (accr[0][nt][3] + brv[0].w) * bf2f(ta.w)
            + (accr[1][nt][0] + brv[1].x) * bf2f(tb.x)
            + (accr[1][nt][1] + brv[1].y) * bf2f(tb.y)
            + (accr[1][nt][2] + brv[1].z) * bf2f(tb.z)
            + (accr[1][nt][3] + brv[1].w) * bf2f(tb.w);
    s += __shfl_xor(s, 16);
    s += __shfl_xor(s, 32);
    if (quad == 0) u_s[e * 12 + wave] = s;
  }
  __syncthreads();   // u_s ready; efs reads long done -> t2_s overlay safe

  // ---- left epilogue: t2[e, r2] = sum_p (left+bl)*u ----
#pragma unroll
  for (int nt = 0; nt < 4; ++nt) {
    int e = nt * 16 + l16;
    float4 uv = *(const float4*)&u_s[e * 12 + 4 * (quad & 1)];
#pragma unroll
    for (int mtl = 0; mtl < 2; ++mtl) {
      float s = (accl[mtl][nt][0] + blv[mtl].x) * uv.x
              + (accl[mtl][nt][1] + blv[mtl].y) * uv.y
              + (accl[mtl][nt][2] + blv[mtl].z) * uv.z
              + (accl[mtl][nt][3] + blv[mtl].w) * uv.w;
      s += __shfl_xor(s, 16);                    // combine p halves (q^1)
      if ((quad & 1) == 0)
        t2_s[e * 36 + 4 * wave + 2 * mtl + (quad >> 1)] = s;
    }
  }
  __syncthreads();

  // ---- final stage: thread -> (e = tid>>3, j = tid&7), elems j*8..j*8+7 ----
  {
    int e = tid >> 3, j = tid & 7;
    float4 t2 = *(const float4*)&t2_s[e * 36 + 4 * j];   // r2 = 4j..4j+3
    float4 b2a = *(const float4*)&b2_s[e * 12 + 0];
    float4 b2b = *(const float4*)&b2_s[e * 12 + 4];
    float v0 = t2.x * b2a.x + t2.y * b2b.x;   // m=2j,   d=0..3
    float v1 = t2.x * b2a.y + t2.y * b2b.y;
    float v2 = t2.x * b2a.z + t2.y * b2b.z;
    float v3 = t2.x * b2a.w + t2.y * b2b.w;
    float v4 = t2.z * b2a.x + t2.w * b2b.x;   // m=2j+1, d=0..3
    float v5 = t2.z * b2a.y + t2.w * b2b.y;
    float v6 = t2.z * b2a.z + t2.w * b2b.z;
    float v7 = t2.z * b2a.w + t2.w * b2b.w;
    if (kmode) {
      // K mode: head (j>>1) half-dot with q, pair-combine, exp, store ex
      int n = *(const int*)(comb + (i0 + e) * 192 + 160);
      const float* qr = qbuf + (size_t)n * 64 + j * 8;
      float4 qa = *(const float4*)&qr[0];
      float4 qc = *(const float4*)&qr[4];
      float s = v0 * qa.x + v1 * qa.y + v2 * qa.z + v3 * qa.w
              + v4 * qc.x + v5 * qc.y + v6 * qc.z + v7 * qc.w;
      s += __shfl_xor(s, 1);                     // combine the two half-heads
      if ((j & 1) == 0)
        exs[(i0 + e) * 4 + (j >> 1)] = __expf(s * 0.25f);
    } else {
      // V mode: pack bf16 kv row
      unsigned q0 = pack_bf16(v0, v1);
      unsigned q1 = pack_bf16(v2, v3);
      unsigned q2 = pack_bf16(v4, v5);
      unsigned q3 = pack_bf16(v6, v7);
      *(uint4*)&kv[(i0 + e) * 64 + j * 8] = make_uint4(q0, q1, q2, q3);
    }
  }
}

// ---------------- attention gather: pure streaming weighted sum -------------
// ex precomputed by conv-K; per edge: num += ex*v, den += ex. No shuffles/exp.
__global__ void __launch_bounds__(256) attn_gather_kernel(
    const float* __restrict__ exs, const u16* __restrict__ kvv,
    const int* __restrict__ rowptr, float* __restrict__ outp) {
  int tid = threadIdx.x;
  int node = blockIdx.x * 4 + (tid >> 6);        // grid 2500 * 4 = NNODES
  int lane = tid & 63, h = lane >> 4;
  int beg = rowptr[node], end = rowptr[node + 1];
  float num = 0.f, den = 0.f;
  int idx = beg;
  for (; idx + 2 <= end; idx += 2) {
    float e0 = exs[(size_t)idx * 4 + h];
    float e1 = exs[(size_t)(idx + 1) * 4 + h];
    float v0 = bf2f(kvv[(size_t)idx * 64 + lane]);
    float v1 = bf2f(kvv[(size_t)(idx + 1) * 64 + lane]);
    num += e0 * v0 + e1 * v1;
    den += e0 + e1;
  }
  if (idx < end) {
    float e0 = exs[(size_t)idx * 4 + h];
    num += e0 * bf2f(kvv[(size_t)idx * 64 + lane]);
    den += e0;
  }
  outp[(size_t)node * 64 + lane] = num / fmaxf(den, 1e-9f);
}

extern "C" void kernel_launch(void* const* d_in, const int* in_sizes, int n_in,
                              void* d_out, int out_size, void* d_ws, size_t ws_size,
                              hipStream_t stream) {
  const float* b1  = (const float*)d_in[0];
  const float* b2  = (const float*)d_in[1];
  const float* ef  = (const float*)d_in[2];
  const float* f   = (const float*)d_in[3];
  const int*   src = (const int*)d_in[4];
  const int*   dst = (const int*)d_in[5];
  const float* qw  = (const float*)d_in[6];
  const float* qb  = (const float*)d_in[7];
  const float* kw1 = (const float*)d_in[8];
  const float* kb1 = (const float*)d_in[9];
  const float* kwl = (const float*)d_in[10];
  const float* kbl = (const float*)d_in[11];
  const float* kwr = (const float*)d_in[12];
  const float* kbr = (const float*)d_in[13];
  const float* vw1 = (const float*)d_in[14];
  const float* vb1 = (const float*)d_in[15];
  const float* vwl = (const float*)d_in[16];
  const float* vbl = (const float*)d_in[17];
  const float* vwr = (const float*)d_in[18];
  const float* vbr = (const float*)d_in[19];
  float* outp = (float*)d_out;

  // workspace layout
  char* ws = (char*)d_ws;
  size_t off = 0;
  auto alloc = [&](size_t bytes) {
    char* p = ws + off;
    off += (bytes + 511) & ~(size_t)511;
    return p;
  };
  u16*   Wsw  = (u16*)  alloc((size_t)4 * 32768 * 2);
  u16*   W1sw = (u16*)  alloc((size_t)2 * 4096 * 2);
  char*  comb = (char*) alloc((size_t)NEDGE * 192);
  u16*   kvv  = (u16*)  alloc((size_t)NEDGE * 64 * 2);
  float* exb  = (float*)alloc((size_t)NEDGE * 4 * 4);
  float* qbuf = (float*)alloc((size_t)NNODES * 64 * 4);
  int*   rowptr = (int*)alloc((size_t)(NNODES + 1) * 4);
  int*   cursor = (int*)alloc((size_t)NNODES * 4);

  // CSR build: one single-block kernel (histogram + scan)
  csr_build_kernel<<<1, 1024, 0, stream>>>(dst, rowptr, cursor);
  // setup: prep_w | prep_w1 | q
  setup_kernel<<<1169, 256, 0, stream>>>(kwr, kwl, vwr, vwl, Wsw,
                                         kw1, vw1, W1sw,
                                         f, qw, qb, qbuf);
  // edge-pass: t | ef | b2 | dstn into CSR-ordered comb records
  fill_t_kernel<<<625, 256, 0, stream>>>(dst, src, f, b1, b2, ef,
                                         cursor, comb);

  // merged conv: even blocks = K (emit ex), odd blocks = V (emit kv rows)
  conv_fused_kernel<<<5000, 512, 0, stream>>>(comb,
                                              W1sw + 0 * 4096, kb1,
                                              Wsw + 0 * 32768, kbr,
                                              Wsw + 1 * 32768, kbl,
                                              W1sw + 1 * 4096, vb1,
                                              Wsw + 2 * 32768, vbr,
                                              Wsw + 3 * 32768, vbl,
                                              qbuf, exb, kvv);

  // attention: pure streaming weighted sum
  attn_gather_kernel<<<2500, 256, 0, stream>>>(exb, kvv, rowptr, outp);
}